// Round 1
// baseline (678.039 us; speedup 1.0000x reference)
//
#include <hip/hip_runtime.h>
#include <stdint.h>

// TreeLSTM cell: h,c,x_f from x@W_iou^T, x@W_f^T, Uh_sum, fc_sum
// N=200000, X=H=256. bf16 MFMA GEMM (tolerance permits), fused epilogue.

typedef __attribute__((ext_vector_type(8))) short bf16x8;
typedef __attribute__((ext_vector_type(4))) float f32x4;
typedef __attribute__((ext_vector_type(4))) unsigned short usx4;

#define N_ROWS 200000
#define HS 256
#define BM 128
#define BK 64
#define LDA 72          // padded row length in bf16 elems (64 + 8)
#define NTHREADS 512

__device__ __forceinline__ unsigned short f2bf(float f) {
    union { float f; uint32_t u; } v; v.f = f;
    uint32_t u = v.u;
    return (unsigned short)((u + 0x7fffu + ((u >> 16) & 1u)) >> 16);
}

__device__ __forceinline__ float fsig(float x) {
    return 1.0f / (1.0f + __expf(-x));
}
__device__ __forceinline__ float ftanh(float x) {
    float e = __expf(2.0f * x);
    return 1.0f - 2.0f / (e + 1.0f);   // -> 1 for x>>0, -1 for x<<0, no NaN
}

__device__ __forceinline__ void write_tile(unsigned short* dst, int sr, int sc,
                                           const float4* v) {
#pragma unroll
    for (int i = 0; i < 4; ++i) {
        usx4 o;
        o.x = f2bf(v[i].x); o.y = f2bf(v[i].y);
        o.z = f2bf(v[i].z); o.w = f2bf(v[i].w);
        *(usx4*)&dst[sr * LDA + (sc + 4 * i) * 4] = o;
    }
}

__global__ __launch_bounds__(NTHREADS)
void treelstm_fused(const float* __restrict__ x,
                    const float* __restrict__ Uh,
                    const float* __restrict__ fc,
                    const float* __restrict__ W_iou,
                    const float* __restrict__ b_iou,
                    const float* __restrict__ W_f,
                    const float* __restrict__ b_f,
                    float* __restrict__ out) {
    __shared__ unsigned short lds_a[2][BM * LDA];
    __shared__ unsigned short lds_b[2][BM * LDA];

    const int tid  = threadIdx.x;
    const int lane = tid & 63;
    const int w    = tid >> 6;          // wave id 0..7, owns rows w*16..w*16+15
    const int bid  = blockIdx.x;
    const int nb   = bid & 7;           // gate-index block: gates nb*32..nb*32+31
    const int mb   = bid >> 3;          // row block

    // ---------------- staging coordinates ----------------
    const int sr = tid >> 2;            // 0..127: tile row (A) / tile col (B)
    const int sc = tid & 3;             // chunk group (float4 chunks sc, sc+4, sc+8, sc+12)

    const int gn = mb * BM + sr;        // global row for A staging
    const float* xrow = x + (size_t)gn * 256;

    // B staging: tile col sr -> weight row. cols laid out [i(0..31)|o|u|f]
    const int g  = sr >> 5;
    const int kg = nb * 32 + (sr & 31);
    const float* wrow = (g < 3) ? (W_iou + (size_t)(g * 256 + kg) * 256)
                                : (W_f   + (size_t)kg * 256);

    f32x4 acc[8];
#pragma unroll
    for (int t = 0; t < 8; ++t) acc[t] = (f32x4){0.f, 0.f, 0.f, 0.f};

    float4 ra[4], rb[4];
    const float4 z4 = make_float4(0.f, 0.f, 0.f, 0.f);

    // ---------------- prologue: stage ks=0 ----------------
    {
        const float4* pa = (const float4*)(xrow);
        const float4* pb = (const float4*)(wrow);
#pragma unroll
        for (int i = 0; i < 4; ++i) {
            ra[i] = (gn < N_ROWS) ? pa[sc + 4 * i] : z4;
            rb[i] = pb[sc + 4 * i];
        }
    }
    write_tile(&lds_a[0][0], sr, sc, ra);
    write_tile(&lds_b[0][0], sr, sc, rb);
    __syncthreads();

    const int arow = w * 16 + (lane & 15);
    const int koff = (lane >> 4) * 8;
    const int bcol = lane & 15;

    int cur = 0;
#pragma unroll
    for (int ks = 0; ks < 4; ++ks) {
        // prefetch next K-step into registers (hides HBM under MFMA)
        if (ks < 3) {
            const float4* pa = (const float4*)(xrow + (ks + 1) * BK);
            const float4* pb = (const float4*)(wrow + (ks + 1) * BK);
#pragma unroll
            for (int i = 0; i < 4; ++i) {
                ra[i] = (gn < N_ROWS) ? pa[sc + 4 * i] : z4;
                rb[i] = pb[sc + 4 * i];
            }
        }
        // compute current K-step: 2 x (1 a-frag, 8 b-frags, 8 MFMA)
#pragma unroll
        for (int kk = 0; kk < 2; ++kk) {
            bf16x8 af = *(const bf16x8*)&lds_a[cur][arow * LDA + kk * 32 + koff];
#pragma unroll
            for (int t = 0; t < 8; ++t) {
                bf16x8 bfr = *(const bf16x8*)&lds_b[cur][(t * 16 + bcol) * LDA + kk * 32 + koff];
                acc[t] = __builtin_amdgcn_mfma_f32_16x16x32_bf16(af, bfr, acc[t], 0, 0, 0);
            }
        }
        if (ks < 3) {
            write_tile(&lds_a[cur ^ 1][0], sr, sc, ra);
            write_tile(&lds_b[cur ^ 1][0], sr, sc, rb);
            __syncthreads();
            cur ^= 1;
        }
    }

    // ---------------- fused epilogue ----------------
    // C/D layout: col = lane&15, row = (lane>>4)*4 + reg  [m89-verified]
    // tiles: t=0,1 -> i ; 2,3 -> o ; 4,5 -> u ; 6,7 -> f
    float* out_h = out;
    float* out_c = out + (size_t)N_ROWS * HS;
    float* out_f = out + 2 * (size_t)N_ROWS * HS;
    const int rquad = (lane >> 4) * 4;

#pragma unroll
    for (int t01 = 0; t01 < 2; ++t01) {
        const int k = nb * 32 + t01 * 16 + bcol;
        const float bi = b_iou[k];
        const float bo = b_iou[256 + k];
        const float bu = b_iou[512 + k];
        const float bff = b_f[k];
#pragma unroll
        for (int r = 0; r < 4; ++r) {
            const int n = mb * BM + w * 16 + rquad + r;
            if (n >= N_ROWS) continue;
            const size_t u3 = (size_t)n * 768;
            const float vi = acc[0 + t01][r] + bi + Uh[u3 + k];
            const float vo = acc[2 + t01][r] + bo + Uh[u3 + 256 + k];
            const float vu = acc[4 + t01][r] + bu + Uh[u3 + 512 + k];
            const float vf = acc[6 + t01][r] + bff;
            const float vc = fsig(vi) * ftanh(vu) + fc[(size_t)n * HS + k];
            const float vh = fsig(vo) * ftanh(vc);
            const size_t oidx = (size_t)n * HS + k;
            out_h[oidx] = vh;
            out_c[oidx] = vc;
            out_f[oidx] = vf;
        }
    }
}

extern "C" void kernel_launch(void* const* d_in, const int* in_sizes, int n_in,
                              void* d_out, int out_size, void* d_ws, size_t ws_size,
                              hipStream_t stream) {
    const float* x     = (const float*)d_in[0];
    const float* Uh    = (const float*)d_in[1];
    const float* fc    = (const float*)d_in[2];
    const float* W_iou = (const float*)d_in[3];
    const float* b_iou = (const float*)d_in[4];
    const float* W_f   = (const float*)d_in[5];
    const float* b_f   = (const float*)d_in[6];
    float* out = (float*)d_out;

    const int mblocks = (N_ROWS + BM - 1) / BM;   // 1563
    dim3 grid(mblocks * 8);
    dim3 block(NTHREADS);
    treelstm_fused<<<grid, block, 0, stream>>>(x, Uh, fc, W_iou, b_iou, W_f, b_f, out);
}